// Round 3
// baseline (478.671 us; speedup 1.0000x reference)
//
#include <hip/hip_runtime.h>

#define NN 50000
#define DIM 64
#define NE 1250000
#define NPARTS 196  // ceil(50000/256)

// ---------------- degree count ----------------
__global__ __launch_bounds__(256) void k_count(const int* __restrict__ row,
                                               int* __restrict__ deg) {
    int stride = gridDim.x * blockDim.x;
    for (int e = blockIdx.x * blockDim.x + threadIdx.x; e < NE; e += stride)
        atomicAdd(&deg[row[e]], 1);
}

// ---------------- hierarchical exclusive scan over deg -> offs ----------------
__global__ __launch_bounds__(256) void k_scan_part(const int* __restrict__ deg,
                                                   int* __restrict__ partial) {
    __shared__ int s[256];
    int t = threadIdx.x;
    int i = blockIdx.x * 256 + t;
    s[t] = (i < NN) ? deg[i] : 0;
    __syncthreads();
    for (int off = 128; off > 0; off >>= 1) {
        if (t < off) s[t] += s[t + off];
        __syncthreads();
    }
    if (t == 0) partial[blockIdx.x] = s[0];
}

__global__ __launch_bounds__(256) void k_scan_top(int* __restrict__ partial) {
    __shared__ int s[256];
    int t = threadIdx.x;
    int v = (t < NPARTS) ? partial[t] : 0;
    s[t] = v;
    __syncthreads();
    for (int off = 1; off < 256; off <<= 1) {
        int x = (t >= off) ? s[t - off] : 0;
        __syncthreads();
        s[t] += x;
        __syncthreads();
    }
    if (t < NPARTS) partial[t] = s[t] - v;  // exclusive block offsets
}

__global__ __launch_bounds__(256) void k_scan_final(const int* __restrict__ deg,
                                                    const int* __restrict__ partial,
                                                    int* __restrict__ offs) {
    __shared__ int s[256];
    int t = threadIdx.x;
    int i = blockIdx.x * 256 + t;
    int v = (i < NN) ? deg[i] : 0;
    s[t] = v;
    __syncthreads();
    for (int off = 1; off < 256; off <<= 1) {
        int x = (t >= off) ? s[t - off] : 0;
        __syncthreads();
        s[t] += x;
        __syncthreads();
    }
    int excl = s[t] - v;
    if (i <= NN) offs[i] = partial[blockIdx.x] + excl;  // offs[NN] = NE (total)
}

// ---------------- CSR fill ----------------
__global__ __launch_bounds__(256) void k_fill(const int* __restrict__ row,
                                              const int* __restrict__ col,
                                              const int* __restrict__ offs,
                                              int* __restrict__ cursor,
                                              int* __restrict__ csr) {
    int stride = gridDim.x * blockDim.x;
    for (int e = blockIdx.x * blockDim.x + threadIdx.x; e < NE; e += stride) {
        int r = row[e];
        int pos = offs[r] + atomicAdd(&cursor[r], 1);
        csr[pos] = col[e];
    }
}

// ---------------- out = 0.25 * x0 ----------------
__global__ __launch_bounds__(256) void k_init_out(const float* __restrict__ x0,
                                                  float* __restrict__ out) {
    int n4 = NN * DIM / 4;
    int stride = gridDim.x * blockDim.x;
    for (int i = blockIdx.x * blockDim.x + threadIdx.x; i < n4; i += stride) {
        float4 v = ((const float4*)x0)[i];
        v.x *= 0.25f; v.y *= 0.25f; v.z *= 0.25f; v.w *= 0.25f;
        ((float4*)out)[i] = v;
    }
}

// ---------------- one propagation layer: x_new[r] = (1/deg[r]) * sum x[col] ----------------
// one 64-lane wave per node, lane = feature dim
__global__ __launch_bounds__(256) void k_layer(const float* __restrict__ xin,
                                               float* __restrict__ xout,
                                               float* __restrict__ out,
                                               const int* __restrict__ offs,
                                               const int* __restrict__ csr) {
    int wave = (blockIdx.x * blockDim.x + threadIdx.x) >> 6;
    int lane = threadIdx.x & 63;
    if (wave >= NN) return;
    int r = wave;
    int beg = offs[r];
    int end = offs[r + 1];
    float acc = 0.f;
    for (int e = beg; e < end; ++e) {
        int c = csr[e];
        acc += xin[c * DIM + lane];
    }
    int d = end - beg;
    float scale = (d > 0) ? (1.0f / (float)d) : 0.0f;
    float v = scale * acc;
    xout[r * DIM + lane] = v;
    out[r * DIM + lane] += 0.25f * v;
}

extern "C" void kernel_launch(void* const* d_in, const int* in_sizes, int n_in,
                              void* d_out, int out_size, void* d_ws, size_t ws_size,
                              hipStream_t stream) {
    const int* edge = (const int*)d_in[0];
    const int* row = edge;        // edge_index[0]
    const int* col = edge + NE;   // edge_index[1]
    const float* emb = (const float*)d_in[1];
    float* out = (float*)d_out;

    // workspace layout (ints, 64-aligned chunks)
    int* deg    = (int*)d_ws;          // 50000 (padded 50048)
    int* cursor = deg + 50048;         // 50000 (padded 50048)
    int* offs   = cursor + 50048;      // 50001 (padded 50112)
    int* partial= offs + 50112;        // 256
    int* csr    = partial + 256;       // 1250000 (padded 1250048)
    float* xa   = (float*)(csr + 1250048);  // 3.2M floats
    float* xb   = xa + NN * DIM;            // 3.2M floats
    // total ~31.2 MB

    hipMemsetAsync(deg, 0, (50048 + 50048) * sizeof(int), stream);  // deg + cursor

    k_count     <<<2048, 256, 0, stream>>>(row, deg);
    k_scan_part <<<NPARTS, 256, 0, stream>>>(deg, partial);
    k_scan_top  <<<1, 256, 0, stream>>>(partial);
    k_scan_final<<<NPARTS, 256, 0, stream>>>(deg, partial, offs);
    k_fill      <<<2048, 256, 0, stream>>>(row, col, offs, cursor, csr);

    k_init_out  <<<2048, 256, 0, stream>>>(emb, out);

    int layer_blocks = (NN * 64) / 256;  // 12500
    k_layer<<<layer_blocks, 256, 0, stream>>>(emb, xa, out, offs, csr);
    k_layer<<<layer_blocks, 256, 0, stream>>>(xa,  xb, out, offs, csr);
    k_layer<<<layer_blocks, 256, 0, stream>>>(xb,  xa, out, offs, csr);
}

// Round 4
// 283.945 us; speedup vs baseline: 1.6858x; 1.6858x over previous
//
#include <hip/hip_runtime.h>

#define NN 50000
#define DIM 64
#define NE 1250000
#define NPARTS 196  // ceil(50000/256)

// ---------------- degree count ----------------
__global__ __launch_bounds__(256) void k_count(const int* __restrict__ row,
                                               int* __restrict__ deg) {
    int stride = gridDim.x * blockDim.x;
    for (int e = blockIdx.x * blockDim.x + threadIdx.x; e < NE; e += stride)
        atomicAdd(&deg[row[e]], 1);
}

// ---------------- hierarchical exclusive scan over deg -> offs ----------------
__global__ __launch_bounds__(256) void k_scan_part(const int* __restrict__ deg,
                                                   int* __restrict__ partial) {
    __shared__ int s[256];
    int t = threadIdx.x;
    int i = blockIdx.x * 256 + t;
    s[t] = (i < NN) ? deg[i] : 0;
    __syncthreads();
    for (int off = 128; off > 0; off >>= 1) {
        if (t < off) s[t] += s[t + off];
        __syncthreads();
    }
    if (t == 0) partial[blockIdx.x] = s[0];
}

__global__ __launch_bounds__(256) void k_scan_top(int* __restrict__ partial) {
    __shared__ int s[256];
    int t = threadIdx.x;
    int v = (t < NPARTS) ? partial[t] : 0;
    s[t] = v;
    __syncthreads();
    for (int off = 1; off < 256; off <<= 1) {
        int x = (t >= off) ? s[t - off] : 0;
        __syncthreads();
        s[t] += x;
        __syncthreads();
    }
    if (t < NPARTS) partial[t] = s[t] - v;  // exclusive block offsets
}

__global__ __launch_bounds__(256) void k_scan_final(const int* __restrict__ deg,
                                                    const int* __restrict__ partial,
                                                    int* __restrict__ offs) {
    __shared__ int s[256];
    int t = threadIdx.x;
    int i = blockIdx.x * 256 + t;
    int v = (i < NN) ? deg[i] : 0;
    s[t] = v;
    __syncthreads();
    for (int off = 1; off < 256; off <<= 1) {
        int x = (t >= off) ? s[t - off] : 0;
        __syncthreads();
        s[t] += x;
        __syncthreads();
    }
    int excl = s[t] - v;
    if (i <= NN) offs[i] = partial[blockIdx.x] + excl;  // offs[NN] = NE (total)
}

// ---------------- CSR fill ----------------
__global__ __launch_bounds__(256) void k_fill(const int* __restrict__ row,
                                              const int* __restrict__ col,
                                              const int* __restrict__ offs,
                                              int* __restrict__ cursor,
                                              int* __restrict__ csr) {
    int stride = gridDim.x * blockDim.x;
    for (int e = blockIdx.x * blockDim.x + threadIdx.x; e < NE; e += stride) {
        int r = row[e];
        int pos = offs[r] + atomicAdd(&cursor[r], 1);
        csr[pos] = col[e];
    }
}

// ---------------- one propagation layer ----------------
// x_new[r] = (1/deg[r]) * sum_{e in CSR[r]} x[col[e]]
// one 64-lane wave per node, lane = feature dim.
// 8-wide unroll: 8 independent index loads then 8 independent gathers per
// iteration -> ~8x memory-level parallelism vs the serial dependent chain.
// FIRST layer also initializes out = 0.25*(x0 + x1), eliminating k_init_out.
template <bool FIRST>
__global__ __launch_bounds__(256) void k_layer(const float* __restrict__ xin,
                                               float* __restrict__ xout,
                                               float* __restrict__ out,
                                               const int* __restrict__ offs,
                                               const int* __restrict__ csr) {
    int wave = (blockIdx.x * blockDim.x + threadIdx.x) >> 6;
    int lane = threadIdx.x & 63;
    if (wave >= NN) return;
    int beg = offs[wave];
    int end = offs[wave + 1];
    const float* xl = xin + lane;

    float a0 = 0.f, a1 = 0.f, a2 = 0.f, a3 = 0.f;
    int e = beg;
    for (; e + 8 <= end; e += 8) {
        int c0 = csr[e + 0], c1 = csr[e + 1], c2 = csr[e + 2], c3 = csr[e + 3];
        int c4 = csr[e + 4], c5 = csr[e + 5], c6 = csr[e + 6], c7 = csr[e + 7];
        float v0 = xl[c0 * DIM];
        float v1 = xl[c1 * DIM];
        float v2 = xl[c2 * DIM];
        float v3 = xl[c3 * DIM];
        float v4 = xl[c4 * DIM];
        float v5 = xl[c5 * DIM];
        float v6 = xl[c6 * DIM];
        float v7 = xl[c7 * DIM];
        a0 += v0 + v4;
        a1 += v1 + v5;
        a2 += v2 + v6;
        a3 += v3 + v7;
    }
    for (; e < end; ++e) a0 += xl[csr[e] * DIM];

    float acc = (a0 + a1) + (a2 + a3);
    int d = end - beg;
    float v = (d > 0) ? acc / (float)d : 0.0f;

    int o = wave * DIM + lane;
    xout[o] = v;
    if (FIRST)
        out[o] = 0.25f * (xin[o] + v);  // xin == emb here: folds k_init_out
    else
        out[o] += 0.25f * v;
}

extern "C" void kernel_launch(void* const* d_in, const int* in_sizes, int n_in,
                              void* d_out, int out_size, void* d_ws, size_t ws_size,
                              hipStream_t stream) {
    const int* edge = (const int*)d_in[0];
    const int* row = edge;        // edge_index[0]
    const int* col = edge + NE;   // edge_index[1]
    const float* emb = (const float*)d_in[1];
    float* out = (float*)d_out;

    // workspace layout (ints, 64-aligned chunks)
    int* deg    = (int*)d_ws;          // 50000 (padded 50048)
    int* cursor = deg + 50048;         // 50000 (padded 50048)
    int* offs   = cursor + 50048;      // 50001 (padded 50112)
    int* partial= offs + 50112;        // 256
    int* csr    = partial + 256;       // 1250000 (padded 1250048)
    float* xa   = (float*)(csr + 1250048);  // 3.2M floats
    float* xb   = xa + NN * DIM;            // 3.2M floats
    // total ~31.2 MB

    hipMemsetAsync(deg, 0, (50048 + 50048) * sizeof(int), stream);  // deg + cursor

    k_count     <<<2048, 256, 0, stream>>>(row, deg);
    k_scan_part <<<NPARTS, 256, 0, stream>>>(deg, partial);
    k_scan_top  <<<1, 256, 0, stream>>>(partial);
    k_scan_final<<<NPARTS, 256, 0, stream>>>(deg, partial, offs);
    k_fill      <<<2048, 256, 0, stream>>>(row, col, offs, cursor, csr);

    int layer_blocks = (NN * 64) / 256;  // 12500
    k_layer<true> <<<layer_blocks, 256, 0, stream>>>(emb, xa, out, offs, csr);
    k_layer<false><<<layer_blocks, 256, 0, stream>>>(xa,  xb, out, offs, csr);
    k_layer<false><<<layer_blocks, 256, 0, stream>>>(xb,  xa, out, offs, csr);
}